// Round 7
// baseline (657.129 us; speedup 1.0000x reference)
//
#include <hip/hip_runtime.h>
#include <math.h>

// BoxDecoder R12: *** MEASUREMENT PROBE v2, intentionally 5x work ***
//
// R11 (3-pass) results: dur 568.8 vs R7 single-pass 456.3 -> marginal warm
// pass Km = 56.2us. 3-pass kernel total = K1 + 2Km still < 255us (not in
// top-5) -> K1 < 143us, F > 313us fixed harness cost. Km=56 < 65us pure-write
// roofline of the 410MB output -> issue rate is NOT the limiter; L3 absorbs
// some rewrites. Remaining unknown: K1 in [86(roofline), 143].
//
// R12 = identical body, PROBE_PASSES 5. Kernel total = K1 + 4Km in
// [310,367]us -> tops the dispatch table -> first direct look at its
// FETCH_SIZE / WRITE_SIZE / VALUBusy / Occupancy. K1 = row_dur - 2*(dur5-dur3).
//
// Committed decision table:
//   dur_us ~675-695 (linearity), kernel row ~310-367us.
//   K1 <= ~95  -> at roofline; revert to single-pass and declare next round.
//   K1 >  ~110 -> headroom; mechanism from counters:
//       FETCH_SIZE >> 100MB       => read amplification
//       WRITE_SIZE >> ~1GB/5pass  => write amplification
//       both nominal + VALUBusy>40% => cold-pass instruction overhead.
//
// Output layout (verified R1-R11): box_tensor [rows,6] f32, then mask [rows],
// then batch_index [rows]; rows = B*A*C, row = t*C + c, t = b*A + a.
// Per t (C==8): 48 floats = 12 float4s; j in [0,12): s=j/3, jm=j%3:
//   jm0 -> (x1,y1,x2,y2) of row 2s
//   jm1 -> (score[2s], 2s+1, x1, y1)
//   jm2 -> (x2, y2, score[2s+1], 2s+2)
//
// Magic divide m=floor(2^38/A)+1 exact for n<=1.6M (verified R1-R3).

#define MAGIC_SHIFT 38
#define PROBE_PASSES 5

typedef float vfloat4 __attribute__((ext_vector_type(4)));

__global__ __launch_bounds__(256) void box_decode_probe5(
    const vfloat4* __restrict__ anchors,  // [A] (cx, cy, w, h)
    const vfloat4* __restrict__ loc,      // [nT]
    const vfloat4* __restrict__ cls4,     // [nT*2]  (C==8)
    const float*   __restrict__ varx_p,
    const float*   __restrict__ vary_p,
    const float*   __restrict__ th_p,
    vfloat4*       __restrict__ out_box4, // [nT*12]
    vfloat4*       __restrict__ out_mask4,// [nT*2]
    vfloat4*       __restrict__ out_bidx4,// [nT*2]
    unsigned nT, unsigned A,
    unsigned long long invA)              // floor(2^38/A)+1
{
    __shared__ vfloat4 s_box[64];    // x1,y1,x2,y2 per t
    __shared__ vfloat4 s_cls4[128];  // 512 scores
    __shared__ float   s_b[64];      // (float)b per t
    const float* s_cls = (const float*)s_cls4;

    const unsigned tid = threadIdx.x;
    const unsigned t0  = blockIdx.x * 64u;

    for (unsigned pass = 0u; pass < PROBE_PASSES; ++pass) {
        // Force re-issue of all global loads each pass (no hoisting).
        asm volatile("" ::: "memory");

        const float varx = *varx_p;
        const float vary = *vary_p;
        const float th   = *th_p;

        if (tid < 64u) {
            unsigned t = t0 + tid;
            if (t < nT) {
                unsigned b = (unsigned)(((unsigned long long)t * invA) >> MAGIC_SHIFT);
                unsigned a = t - b * A;
                vfloat4 anc = anchors[a];
                vfloat4 lp  = loc[t];
                float x = fmaf(lp.x * varx, anc.z, anc.x);
                float y = fmaf(lp.y * varx, anc.w, anc.y);
                float w = expf(lp.z * vary) * anc.z;
                float h = expf(lp.w * vary) * anc.w;
                vfloat4 bx;
                bx.x = fmaf(w, -0.5f, x);
                bx.y = fmaf(h, -0.5f, y);
                bx.z = fmaf(w,  0.5f, x);
                bx.w = fmaf(h,  0.5f, y);
                s_box[tid] = bx;
                s_b[tid]   = (float)b;
            }
        } else if (tid < 192u) {
            unsigned i  = tid - 64u;          // 0..127
            unsigned gi = t0 * 2u + i;
            if (gi < nT * 2u)
                s_cls4[i] = cls4[gi];
        }
        __syncthreads();

        // ---- Phase 2: 768 box float4s, dense & coalesced ---------------
        {
            const unsigned nt_blk = (nT - t0 < 64u) ? (nT - t0) : 64u;
            const unsigned lim    = nt_blk * 12u;
            const unsigned base   = t0 * 12u;
#pragma unroll
            for (unsigned k = 0u; k < 3u; ++k) {
                unsigned lg = k * 256u + tid;          // 0..767
                if (lg < lim) {
                    unsigned lt = lg / 12u;            // const-div -> magic
                    unsigned j  = lg - lt * 12u;
                    unsigned s  = j / 3u;
                    unsigned jm = j - s * 3u;
                    vfloat4 bx  = s_box[lt];           // broadcast read
                    float sc0 = s_cls[lt * 8u + 2u * s];
                    float sc1 = s_cls[lt * 8u + 2u * s + 1u];
                    float l0  = (float)(2u * s + 1u);
                    float l1  = (float)(2u * s + 2u);
                    bool j0 = (jm == 0u);
                    bool j1 = (jm == 1u);
                    vfloat4 r;
                    r.x = j0 ? bx.x : (j1 ? sc0  : bx.z);
                    r.y = j0 ? bx.y : (j1 ? l0   : bx.w);
                    r.z = j0 ? bx.z : (j1 ? bx.x : sc1);
                    r.w = j0 ? bx.w : (j1 ? bx.y : l1);
                    out_box4[base + lg] = r;
                }
            }
        }

        // ---- Phase 3: mask + bidx as dense float4 stores ---------------
        {
            const unsigned nt_blk = (nT - t0 < 64u) ? (nT - t0) : 64u;
            const unsigned lim    = nt_blk * 2u;       // float4 count
            const unsigned mbase  = t0 * 2u;
            if (tid < 128u) {
                unsigned i = tid;
                if (i < lim) {
                    vfloat4 c = s_cls4[i];
                    vfloat4 m;
                    m.x = (c.x >= th) ? 1.0f : 0.0f;
                    m.y = (c.y >= th) ? 1.0f : 0.0f;
                    m.z = (c.z >= th) ? 1.0f : 0.0f;
                    m.w = (c.w >= th) ? 1.0f : 0.0f;
                    out_mask4[mbase + i] = m;
                }
            } else {
                unsigned i = tid - 128u;
                if (i < lim) {
                    float bf = s_b[i >> 1];   // 4 rows per float4, 8 rows per t
                    vfloat4 bb = {bf, bf, bf, bf};
                    out_bidx4[mbase + i] = bb;
                }
            }
        }

        // Guard LDS reuse across passes.
        __syncthreads();
    }
}

// ---------------- Generic fallback (any C with (6C)%4==0) ---------------
__global__ __launch_bounds__(256) void box_decode_kernel(
    const float4* __restrict__ anchors,
    const float4* __restrict__ loc,
    const float*  __restrict__ cls,
    const float*  __restrict__ varx_p,
    const float*  __restrict__ vary_p,
    const float*  __restrict__ th_p,
    vfloat4*      __restrict__ out_box4,
    float*        __restrict__ out_mask,
    float*        __restrict__ out_bidx,
    unsigned n4, unsigned A, unsigned C, unsigned f4_per_t,
    unsigned long long invA, unsigned long long invF)
{
    unsigned g = blockIdx.x * 256u + threadIdx.x;
    if (g >= n4) return;
    unsigned t  = (unsigned)(((unsigned long long)g * invF) >> MAGIC_SHIFT);
    unsigned j  = g - t * f4_per_t;
    unsigned b  = (unsigned)(((unsigned long long)t * invA) >> MAGIC_SHIFT);
    unsigned a  = t - b * A;
    unsigned s  = j / 3u;
    unsigned jm = j - s * 3u;
    float varx = *varx_p, vary = *vary_p, th = *th_p;
    float4 anc = anchors[a];
    float4 lp  = loc[t];
    float x = fmaf(lp.x * varx, anc.z, anc.x);
    float y = fmaf(lp.y * varx, anc.w, anc.y);
    float w = expf(lp.z * vary) * anc.z;
    float h = expf(lp.w * vary) * anc.w;
    float x1 = fmaf(w, -0.5f, x);
    float y1 = fmaf(h, -0.5f, y);
    float x2 = fmaf(w,  0.5f, x);
    float y2 = fmaf(h,  0.5f, y);
    unsigned r0 = t * C + 2u * s;
    float bf = (float)b;
    vfloat4 r;
    if (jm == 0u) {
        r.x = x1; r.y = y1; r.z = x2; r.w = y2;
    } else if (jm == 1u) {
        float sc0 = cls[r0];
        r.x = sc0; r.y = (float)(2u * s + 1u); r.z = x1; r.w = y1;
        out_mask[r0] = (sc0 >= th) ? 1.0f : 0.0f;
        out_bidx[r0] = bf;
    } else {
        float sc1 = cls[r0 + 1u];
        r.x = x2; r.y = y2; r.z = sc1; r.w = (float)(2u * s + 2u);
        out_mask[r0 + 1u] = (sc1 >= th) ? 1.0f : 0.0f;
        out_bidx[r0 + 1u] = bf;
    }
    out_box4[g] = r;
}

extern "C" void kernel_launch(void* const* d_in, const int* in_sizes, int n_in,
                              void* d_out, int out_size, void* d_ws, size_t ws_size,
                              hipStream_t stream) {
    const float* anchors = (const float*)d_in[0];
    const float* loc     = (const float*)d_in[1];
    const float* cls     = (const float*)d_in[2];
    const float* varx_p  = (const float*)d_in[3];
    const float* vary_p  = (const float*)d_in[4];
    const float* th_p    = (const float*)d_in[5];

    unsigned A = (unsigned)(in_sizes[0] / 4);
    unsigned B = (unsigned)((unsigned)in_sizes[1] / (4u * A));
    unsigned C = (unsigned)((unsigned)in_sizes[2] / (A * B));
    unsigned nT = B * A;
    unsigned rows = nT * C;

    float* out_box  = (float*)d_out;
    float* out_mask = out_box + (size_t)rows * 6;
    float* out_bidx = out_mask + rows;

    unsigned long long invA = ((1ULL << MAGIC_SHIFT) / A) + 1ULL;

    if (C == 8u) {
        unsigned nb = (nT + 63u) / 64u;    // one block per 64-t chunk
        box_decode_probe5<<<dim3(nb), dim3(256), 0, stream>>>(
            (const vfloat4*)anchors, (const vfloat4*)loc, (const vfloat4*)cls,
            varx_p, vary_p, th_p,
            (vfloat4*)out_box, (vfloat4*)out_mask, (vfloat4*)out_bidx,
            nT, A, invA);
    } else {
        unsigned f4_per_t = (6u * C) / 4u;
        unsigned n4 = rows * 6u / 4u;
        unsigned long long invF = ((1ULL << MAGIC_SHIFT) / f4_per_t) + 1ULL;
        unsigned nb = (n4 + 255u) / 256u;
        box_decode_kernel<<<dim3(nb), dim3(256), 0, stream>>>(
            (const float4*)anchors, (const float4*)loc, cls,
            varx_p, vary_p, th_p,
            (vfloat4*)out_box, out_mask, out_bidx,
            n4, A, C, f4_per_t, invA, invF);
    }
}

// Round 8
// 450.893 us; speedup vs baseline: 1.4574x; 1.4574x over previous
//
#include <hip/hip_runtime.h>
#include <math.h>

// BoxDecoder R13 = R6 reverted (session-best single-pass, 451.3us), after the
// R11/R12 measurement probes established the roofline case:
//
//   * 5-pass probe kernel measured directly (R12): 5.90 TB/s = 74% HBM peak,
//     94% of the poison fill's 6.3 TB/s achieved ceiling on this chip.
//   * FETCH_SIZE 114MB / 5 passes = one cold 78MB read -> NO read
//     amplification. WRITE_SIZE 1.652GB < 2.048GB logical -> NO write
//     amplification (L3 absorbs).
//   * Warm pass = 44-50us < 65us pure-write roofline -> instruction issue
//     exonerated (L3-assisted).
//   * Cold pass K1 ~ 110-130us = 77us mixed-traffic roofline + ~40us of the
//     poison fill's dirty-L3 drain (256MB @ 6.3TB/s) contending at kernel
//     start -- harness-structural, not kernel-attributable.
//   * Harness fixed cost F > 313us (R11 bound: 3-pass kernel < 255us floor).
//
// Conclusion: traffic minimal, BW at the achieved ceiling, remaining dur_us
// is harness fill + restores. This file restores the best verified kernel.
//
// Structure (C==8; generic fallback below):
//   Phase 1a: lanes 0..63   decode t0+lane once -> LDS (box float4 + b)
//   Phase 1b: lanes 64..191 stage 128 float4 of cls (512 floats) -> LDS
//   Phase 2 : all 256 lanes write the 768 box float4s of the block
//             (branch-free build from LDS broadcasts), dense nt stores
//   Phase 3 : lanes 0..127 write mask as 128 dense float4 nt stores,
//             lanes 128..255 write bidx as 128 dense float4 nt stores
//
// Output layout (verified R1-R12): box_tensor [rows,6] floats, then mask
// [rows], then batch_index [rows]; rows = B*A*C, row = t*C + c.
// Per t, 48 floats = 12 float4s; j in [0,12): s=j/3, jm=j%3:
//   jm0 -> (x1,y1,x2,y2) of row 2s
//   jm1 -> (score[2s], 2s+1, x1, y1)
//   jm2 -> (x2, y2, score[2s+1], 2s+2)
//
// Magic divide m=floor(2^38/A)+1 exact for n<=1.6M (verified R1-R3).

#define MAGIC_SHIFT 38

typedef float vfloat4 __attribute__((ext_vector_type(4)));

__global__ __launch_bounds__(256) void box_decode_coop(
    const vfloat4* __restrict__ anchors,  // [A] (cx, cy, w, h)
    const vfloat4* __restrict__ loc,      // [nT]
    const vfloat4* __restrict__ cls4,     // [nT*2]  (C==8 -> 8 floats/t)
    const float*   __restrict__ varx_p,
    const float*   __restrict__ vary_p,
    const float*   __restrict__ th_p,
    vfloat4*       __restrict__ out_box4, // [nT*12]
    vfloat4*       __restrict__ out_mask4,// [nT*2]
    vfloat4*       __restrict__ out_bidx4,// [nT*2]
    unsigned nT, unsigned A,
    unsigned long long invA)              // floor(2^38/A)+1
{
    __shared__ vfloat4 s_box[64];    // x1,y1,x2,y2 per t
    __shared__ vfloat4 s_cls4[128];  // 512 scores
    __shared__ float   s_b[64];      // (float)b per t
    const float* s_cls = (const float*)s_cls4;

    const unsigned tid = threadIdx.x;
    const unsigned t0  = blockIdx.x * 64u;

    const float varx = *varx_p;
    const float vary = *vary_p;
    const float th   = *th_p;

    if (tid < 64u) {
        unsigned t = t0 + tid;
        if (t < nT) {
            unsigned b = (unsigned)(((unsigned long long)t * invA) >> MAGIC_SHIFT);
            unsigned a = t - b * A;
            vfloat4 anc = anchors[a];                            // reused across b: cached
            vfloat4 lp  = __builtin_nontemporal_load(&loc[t]);   // streamed once
            float x = fmaf(lp.x * varx, anc.z, anc.x);
            float y = fmaf(lp.y * varx, anc.w, anc.y);
            float w = expf(lp.z * vary) * anc.z;
            float h = expf(lp.w * vary) * anc.w;
            vfloat4 bx;
            bx.x = fmaf(w, -0.5f, x);
            bx.y = fmaf(h, -0.5f, y);
            bx.z = fmaf(w,  0.5f, x);
            bx.w = fmaf(h,  0.5f, y);
            s_box[tid] = bx;
            s_b[tid]   = (float)b;
        }
    } else if (tid < 192u) {
        unsigned i  = tid - 64u;          // 0..127
        unsigned gi = t0 * 2u + i;
        if (gi < nT * 2u)
            s_cls4[i] = __builtin_nontemporal_load(&cls4[gi]);
    }
    __syncthreads();

    // ---- Phase 2: 768 box float4s, dense & coalesced -------------------
    {
        const unsigned nt_blk = (nT - t0 < 64u) ? (nT - t0) : 64u;
        const unsigned lim    = nt_blk * 12u;
        const unsigned base   = t0 * 12u;
#pragma unroll
        for (unsigned k = 0u; k < 3u; ++k) {
            unsigned lg = k * 256u + tid;          // 0..767
            if (lg < lim) {
                unsigned lt = lg / 12u;            // const-div -> magic
                unsigned j  = lg - lt * 12u;
                unsigned s  = j / 3u;
                unsigned jm = j - s * 3u;
                vfloat4 bx  = s_box[lt];           // broadcast read
                float sc0 = s_cls[lt * 8u + 2u * s];
                float sc1 = s_cls[lt * 8u + 2u * s + 1u];
                float l0  = (float)(2u * s + 1u);
                float l1  = (float)(2u * s + 2u);
                bool j0 = (jm == 0u);
                bool j1 = (jm == 1u);
                vfloat4 r;
                r.x = j0 ? bx.x : (j1 ? sc0  : bx.z);
                r.y = j0 ? bx.y : (j1 ? l0   : bx.w);
                r.z = j0 ? bx.z : (j1 ? bx.x : sc1);
                r.w = j0 ? bx.w : (j1 ? bx.y : l1);
                __builtin_nontemporal_store(r, &out_box4[base + lg]);
            }
        }
    }

    // ---- Phase 3: mask + bidx as dense float4 nt stores ----------------
    {
        const unsigned nt_blk = (nT - t0 < 64u) ? (nT - t0) : 64u;
        const unsigned lim    = nt_blk * 2u;       // float4 count
        const unsigned mbase  = t0 * 2u;
        if (tid < 128u) {
            unsigned i = tid;
            if (i < lim) {
                vfloat4 c = s_cls4[i];
                vfloat4 m;
                m.x = (c.x >= th) ? 1.0f : 0.0f;
                m.y = (c.y >= th) ? 1.0f : 0.0f;
                m.z = (c.z >= th) ? 1.0f : 0.0f;
                m.w = (c.w >= th) ? 1.0f : 0.0f;
                __builtin_nontemporal_store(m, &out_mask4[mbase + i]);
            }
        } else {
            unsigned i = tid - 128u;
            if (i < lim) {
                float bf = s_b[i >> 1];            // 4 rows per float4, 8 rows per t
                vfloat4 bb = {bf, bf, bf, bf};
                __builtin_nontemporal_store(bb, &out_bidx4[mbase + i]);
            }
        }
    }
}

// ---------------- Generic fallback (any C with (6C)%4==0) ---------------
__global__ __launch_bounds__(256) void box_decode_kernel(
    const float4* __restrict__ anchors,
    const float4* __restrict__ loc,
    const float*  __restrict__ cls,
    const float*  __restrict__ varx_p,
    const float*  __restrict__ vary_p,
    const float*  __restrict__ th_p,
    vfloat4*      __restrict__ out_box4,
    float*        __restrict__ out_mask,
    float*        __restrict__ out_bidx,
    unsigned n4, unsigned A, unsigned C, unsigned f4_per_t,
    unsigned long long invA, unsigned long long invF)
{
    unsigned g = blockIdx.x * 256u + threadIdx.x;
    if (g >= n4) return;
    unsigned t  = (unsigned)(((unsigned long long)g * invF) >> MAGIC_SHIFT);
    unsigned j  = g - t * f4_per_t;
    unsigned b  = (unsigned)(((unsigned long long)t * invA) >> MAGIC_SHIFT);
    unsigned a  = t - b * A;
    unsigned s  = j / 3u;
    unsigned jm = j - s * 3u;
    float varx = *varx_p, vary = *vary_p, th = *th_p;
    float4 anc = anchors[a];
    float4 lp  = loc[t];
    float x = fmaf(lp.x * varx, anc.z, anc.x);
    float y = fmaf(lp.y * varx, anc.w, anc.y);
    float w = expf(lp.z * vary) * anc.z;
    float h = expf(lp.w * vary) * anc.w;
    float x1 = fmaf(w, -0.5f, x);
    float y1 = fmaf(h, -0.5f, y);
    float x2 = fmaf(w,  0.5f, x);
    float y2 = fmaf(h,  0.5f, y);
    unsigned r0 = t * C + 2u * s;
    float bf = (float)b;
    vfloat4 r;
    if (jm == 0u) {
        r.x = x1; r.y = y1; r.z = x2; r.w = y2;
    } else if (jm == 1u) {
        float sc0 = cls[r0];
        r.x = sc0; r.y = (float)(2u * s + 1u); r.z = x1; r.w = y1;
        __builtin_nontemporal_store((sc0 >= th) ? 1.0f : 0.0f, &out_mask[r0]);
        __builtin_nontemporal_store(bf, &out_bidx[r0]);
    } else {
        float sc1 = cls[r0 + 1u];
        r.x = x2; r.y = y2; r.z = sc1; r.w = (float)(2u * s + 2u);
        __builtin_nontemporal_store((sc1 >= th) ? 1.0f : 0.0f, &out_mask[r0 + 1u]);
        __builtin_nontemporal_store(bf, &out_bidx[r0 + 1u]);
    }
    __builtin_nontemporal_store(r, &out_box4[g]);
}

extern "C" void kernel_launch(void* const* d_in, const int* in_sizes, int n_in,
                              void* d_out, int out_size, void* d_ws, size_t ws_size,
                              hipStream_t stream) {
    const float* anchors = (const float*)d_in[0];
    const float* loc     = (const float*)d_in[1];
    const float* cls     = (const float*)d_in[2];
    const float* varx_p  = (const float*)d_in[3];
    const float* vary_p  = (const float*)d_in[4];
    const float* th_p    = (const float*)d_in[5];

    unsigned A = (unsigned)(in_sizes[0] / 4);
    unsigned B = (unsigned)((unsigned)in_sizes[1] / (4u * A));
    unsigned C = (unsigned)((unsigned)in_sizes[2] / (A * B));
    unsigned nT = B * A;
    unsigned rows = nT * C;

    float* out_box  = (float*)d_out;
    float* out_mask = out_box + (size_t)rows * 6;
    float* out_bidx = out_mask + rows;

    unsigned long long invA = ((1ULL << MAGIC_SHIFT) / A) + 1ULL;

    if (C == 8u) {
        unsigned nb = (nT + 63u) / 64u;
        box_decode_coop<<<dim3(nb), dim3(256), 0, stream>>>(
            (const vfloat4*)anchors, (const vfloat4*)loc, (const vfloat4*)cls,
            varx_p, vary_p, th_p,
            (vfloat4*)out_box, (vfloat4*)out_mask, (vfloat4*)out_bidx,
            nT, A, invA);
    } else {
        unsigned f4_per_t = (6u * C) / 4u;
        unsigned n4 = rows * 6u / 4u;
        unsigned long long invF = ((1ULL << MAGIC_SHIFT) / f4_per_t) + 1ULL;
        unsigned nb = (n4 + 255u) / 256u;
        box_decode_kernel<<<dim3(nb), dim3(256), 0, stream>>>(
            (const float4*)anchors, (const float4*)loc, cls,
            varx_p, vary_p, th_p,
            (vfloat4*)out_box, out_mask, out_bidx,
            n4, A, C, f4_per_t, invA, invF);
    }
}